// Round 7
// baseline (464.495 us; speedup 1.0000x reference)
//
#include <hip/hip_runtime.h>
#include <hip/hip_bf16.h>
#include <math.h>
#include <stdint.h>

typedef unsigned int u32;
typedef unsigned long long u64;
typedef unsigned short u16;
typedef __attribute__((ext_vector_type(8))) short bf16x8;
typedef __attribute__((ext_vector_type(4))) float f32x4;

#define NROWS 16384
#define KCB   2048
#define DIMS  256

// ---------------- threefry2x32-20, key = (0, 42)  (jax.random.key(42)) ----
__device__ __forceinline__ u32 rotl32(u32 x, int r) { return (x << r) | (x >> (32 - r)); }

__device__ __forceinline__ uint2 threefry42(u32 x0, u32 x1) {
  const u32 ks0 = 0u, ks1 = 42u, ks2 = 0x1BD11BDAu ^ 42u;
  x0 += ks0; x1 += ks1;
  x0 += x1; x1 = rotl32(x1, 13); x1 ^= x0;
  x0 += x1; x1 = rotl32(x1, 15); x1 ^= x0;
  x0 += x1; x1 = rotl32(x1, 26); x1 ^= x0;
  x0 += x1; x1 = rotl32(x1, 6);  x1 ^= x0;
  x0 += ks1; x1 += ks2 + 1u;
  x0 += x1; x1 = rotl32(x1, 17); x1 ^= x0;
  x0 += x1; x1 = rotl32(x1, 29); x1 ^= x0;
  x0 += x1; x1 = rotl32(x1, 16); x1 ^= x0;
  x0 += x1; x1 = rotl32(x1, 24); x1 ^= x0;
  x0 += ks2; x1 += ks0 + 2u;
  x0 += x1; x1 = rotl32(x1, 13); x1 ^= x0;
  x0 += x1; x1 = rotl32(x1, 15); x1 ^= x0;
  x0 += x1; x1 = rotl32(x1, 26); x1 ^= x0;
  x0 += x1; x1 = rotl32(x1, 6);  x1 ^= x0;
  x0 += ks0; x1 += ks1 + 3u;
  x0 += x1; x1 = rotl32(x1, 17); x1 ^= x0;
  x0 += x1; x1 = rotl32(x1, 29); x1 ^= x0;
  x0 += x1; x1 = rotl32(x1, 16); x1 ^= x0;
  x0 += x1; x1 = rotl32(x1, 24); x1 ^= x0;
  x0 += ks1; x1 += ks2 + 4u;
  x0 += x1; x1 = rotl32(x1, 13); x1 ^= x0;
  x0 += x1; x1 = rotl32(x1, 15); x1 ^= x0;
  x0 += x1; x1 = rotl32(x1, 26); x1 ^= x0;
  x0 += x1; x1 = rotl32(x1, 6);  x1 ^= x0;
  x0 += ks2; x1 += ks0 + 5u;
  return make_uint2(x0, x1);
}

__device__ __forceinline__ u32 tf_bits_partitionable(u32 i) {
  uint2 y = threefry42(0u, i);
  return y.x ^ y.y;
}

// jax uniform(minval=FLT_MIN,maxval=1) then gumbel = -log(-log(u)), fp32
__device__ __forceinline__ float gumbel_from_bits(u32 bits) {
  float u = __uint_as_float((bits >> 9) | 0x3f800000u) - 1.0f;
  u = (u == 0.0f) ? 1.17549435082228751e-38f : u;
  return -logf(-logf(u));
}

__device__ __forceinline__ short f2bf_s(float f) {
  union { __hip_bfloat16 h; short s; } cv; cv.h = __float2bfloat16(f); return cv.s;
}
__device__ __forceinline__ float bfs2f(short s) {
  union { __hip_bfloat16 h; short s2; } cv; cv.s2 = s; return __bfloat162float(cv.h);
}

// numpy pairwise sum-of-squares, 128 floats, float4 loads, exact np order
__device__ __forceinline__ float np_sq128_v(const float4* __restrict__ p4) {
  float r0 = 0.f, r1 = 0.f, r2 = 0.f, r3 = 0.f, r4 = 0.f, r5 = 0.f, r6 = 0.f, r7 = 0.f;
  for (int i8 = 0; i8 < 16; ++i8) {
    float4 x0 = p4[2 * i8], x1 = p4[2 * i8 + 1];
    r0 = __fadd_rn(r0, __fmul_rn(x0.x, x0.x));
    r1 = __fadd_rn(r1, __fmul_rn(x0.y, x0.y));
    r2 = __fadd_rn(r2, __fmul_rn(x0.z, x0.z));
    r3 = __fadd_rn(r3, __fmul_rn(x0.w, x0.w));
    r4 = __fadd_rn(r4, __fmul_rn(x1.x, x1.x));
    r5 = __fadd_rn(r5, __fmul_rn(x1.y, x1.y));
    r6 = __fadd_rn(r6, __fmul_rn(x1.z, x1.z));
    r7 = __fadd_rn(r7, __fmul_rn(x1.w, x1.w));
  }
  return __fadd_rn(__fadd_rn(__fadd_rn(r0, r1), __fadd_rn(r2, r3)),
                   __fadd_rn(__fadd_rn(r4, r5), __fadd_rn(r6, r7)));
}

// ---------------- k_rowstats: A_n = sum x^2 (np pairwise order) ---------
__global__ __launch_bounds__(256) void k_rowstats(const float* __restrict__ flat,
                                                  float* __restrict__ rowA,
                                                  float* __restrict__ rnorm) {
  int n = blockIdx.x * 256 + threadIdx.x;
  const float4* p4 = (const float4*)(flat + (size_t)n * DIMS);
  float acc = __fadd_rn(np_sq128_v(p4), np_sq128_v(p4 + 32));
  rowA[n] = acc;
  rnorm[n] = sqrtf(acc);
}

// ---------------- k_codestats: repar fp32 + bf16 hi/lo split; sqk -------
__global__ __launch_bounds__(64) void k_codestats(const float* __restrict__ cb,
                                                  const float* __restrict__ cmean,
                                                  const float* __restrict__ cstd,
                                                  float* __restrict__ repar,
                                                  u16* __restrict__ reparH,
                                                  u16* __restrict__ reparL,
                                                  float* __restrict__ sqk,
                                                  float* __restrict__ ncn,
                                                  int* __restrict__ hist,
                                                  u64* __restrict__ row_max) {
  __shared__ float row[DIMS];
  int k = blockIdx.x;
  int lane = threadIdx.x;
  int gid = k * 64 + lane;
  if (gid < KCB) hist[gid] = 0;
  if (gid < NROWS) row_max[gid] = 0ull;
  float4 c = ((const float4*)(cb + (size_t)k * DIMS))[lane];
  float4 m = ((const float4*)cmean)[lane];
  float4 sd = ((const float4*)cstd)[lane];
  float4 r;
  r.x = __fadd_rn(m.x, __fmul_rn(sd.x, c.x));
  r.y = __fadd_rn(m.y, __fmul_rn(sd.y, c.y));
  r.z = __fadd_rn(m.z, __fmul_rn(sd.z, c.z));
  r.w = __fadd_rn(m.w, __fmul_rn(sd.w, c.w));
  ((float4*)(repar + (size_t)k * DIMS))[lane] = r;
  ((float4*)row)[lane] = r;
  // bf16 hi/lo split (identical math to the k_main staging that passed R6)
  float rv[4] = {r.x, r.y, r.z, r.w};
  ushort4 hi, lo;
  unsigned short hs[4], ls[4];
#pragma unroll
  for (int j = 0; j < 4; ++j) {
    short h = f2bf_s(rv[j]);
    hs[j] = (unsigned short)h;
    ls[j] = (unsigned short)f2bf_s(__fsub_rn(rv[j], bfs2f(h)));
  }
  hi.x = hs[0]; hi.y = hs[1]; hi.z = hs[2]; hi.w = hs[3];
  lo.x = ls[0]; lo.y = ls[1]; lo.z = ls[2]; lo.w = ls[3];
  ((ushort4*)(reparH + (size_t)k * DIMS))[lane] = hi;
  ((ushort4*)(reparL + (size_t)k * DIMS))[lane] = lo;
  __syncthreads();
  if (lane == 0) {
    // np pairwise on the row (same order as before)
    float acc = __fadd_rn(np_sq128_v((const float4*)row),
                          np_sq128_v((const float4*)row + 32));
    sqk[k] = acc;
    ncn[k] = sqrtf(acc);
  }
}

// ---------------- k_main: LDS-free bf16-split MFMA + gumbel argmax ------
// 256 thr = 4 waves; wave w: rows r0+w*16..+15, all 64 cols of this block.
// A fp32 direct load + on-the-fly split; B from precomputed reparH/L.
__global__ __launch_bounds__(256, 8) void k_main(const float* __restrict__ flat,
                                                 const u16* __restrict__ reparH,
                                                 const u16* __restrict__ reparL,
                                                 const float* __restrict__ rowA,
                                                 const float* __restrict__ sqk,
                                                 u64* __restrict__ row_max) {
  const int t = threadIdx.x;
  const int wid = t >> 6, lane = t & 63;
  const int r = lane & 15, q = lane >> 4;
  const int r0 = blockIdx.y * 64;
  const int c0 = blockIdx.x * 64;
  const int arow = r0 + wid * 16 + r;

  f32x4 acc[4] = {{0.f,0.f,0.f,0.f},{0.f,0.f,0.f,0.f},
                  {0.f,0.f,0.f,0.f},{0.f,0.f,0.f,0.f}};

  const float* ap = flat + (size_t)arow * DIMS + q * 8;
  const u16* bhp = reparH + (size_t)(c0 + r) * DIMS + q * 8;
  const u16* blp = reparL + (size_t)(c0 + r) * DIMS + q * 8;

  for (int sl = 0; sl < 8; ++sl) {
    float4 a0 = ((const float4*)(ap + sl * 32))[0];
    float4 a1 = ((const float4*)(ap + sl * 32))[1];
    float av[8] = {a0.x, a0.y, a0.z, a0.w, a1.x, a1.y, a1.z, a1.w};
    bf16x8 ah, al;
#pragma unroll
    for (int j = 0; j < 8; ++j) {
      short h = f2bf_s(av[j]);
      ah[j] = h;
      al[j] = f2bf_s(__fsub_rn(av[j], bfs2f(h)));
    }
#pragma unroll
    for (int tile = 0; tile < 4; ++tile) {
      bf16x8 bh = *(const bf16x8*)(bhp + (size_t)tile * 16 * DIMS + sl * 32);
      bf16x8 bl = *(const bf16x8*)(blp + (size_t)tile * 16 * DIMS + sl * 32);
      acc[tile] = __builtin_amdgcn_mfma_f32_16x16x32_bf16(ah, bh, acc[tile], 0, 0, 0);
      acc[tile] = __builtin_amdgcn_mfma_f32_16x16x32_bf16(ah, bl, acc[tile], 0, 0, 0);
      acc[tile] = __builtin_amdgcn_mfma_f32_16x16x32_bf16(al, bh, acc[tile], 0, 0, 0);
    }
  }

  // epilogue: C/D layout col=lane&15, row=q*4+reg  (identical to R6)
  const int nbase = r0 + wid * 16 + q * 4;
  float An[4];
#pragma unroll
  for (int reg = 0; reg < 4; ++reg) An[reg] = rowA[nbase + reg];
  float bv[4];
  int bk[4];
#pragma unroll
  for (int reg = 0; reg < 4; ++reg) { bv[reg] = -3.4e38f; bk[reg] = 0; }

#pragma unroll
  for (int tile = 0; tile < 4; ++tile) {
    int col = c0 + tile * 16 + r;
    float sqa = sqk[col];
#pragma unroll
    for (int reg = 0; reg < 4; ++reg) {
      float dot = acc[tile][reg];
      float t3 = __fsub_rn(An[reg], __fmul_rn(2.0f, dot));
      float t4 = __fadd_rn(t3, sqa);
      u32 bits = tf_bits_partitionable((u32)(nbase + reg) * 2048u + (u32)col);
      float g = gumbel_from_bits(bits);
      float v = __fsub_rn(g, t4);
      if (v > bv[reg] || (v == bv[reg] && col < bk[reg])) { bv[reg] = v; bk[reg] = col; }
    }
  }

#pragma unroll
  for (int reg = 0; reg < 4; ++reg) {
#pragma unroll
    for (int m = 1; m < 16; m <<= 1) {
      float ov = __shfl_xor(bv[reg], m);
      int ok = __shfl_xor(bk[reg], m);
      if (ov > bv[reg] || (ov == bv[reg] && ok < bk[reg])) { bv[reg] = ov; bk[reg] = ok; }
    }
    if (r == 0) {
      u32 s = __float_as_uint(bv[reg]);
      u32 uo = (s & 0x80000000u) ? ~s : (s | 0x80000000u);
      u64 key = ((u64)uo << 32) | (u64)(u32)(2047 - bk[reg]);  // max v, then min k
      atomicMax(&row_max[nbase + reg], key);
    }
  }
}

// ---------------- k_quant: decode idx, STE write, mse/cos, hist ---------
__global__ __launch_bounds__(256) void k_quant(const float* __restrict__ flat,
                                               const float* __restrict__ repar,
                                               const u64* __restrict__ row_max,
                                               const float* __restrict__ rnorm,
                                               const float* __restrict__ ncn,
                                               float* __restrict__ outq,
                                               float* __restrict__ out_idx,
                                               double* __restrict__ qp_mse,
                                               double* __restrict__ qp_cos,
                                               int* __restrict__ hist) {
  int t = threadIdx.x, w = t >> 6, lane = t & 63;
  int n = blockIdx.x * 4 + w;
  u64 key = row_max[n];
  int k = 2047 - (int)(u32)(key & 0xFFFFFFFFull);
  k = (k < 0) ? 0 : (k > (KCB - 1) ? (KCB - 1) : k);
  float4 q = ((const float4*)(repar + (size_t)k * DIMS))[lane];
  float4 x = ((const float4*)(flat + (size_t)n * DIMS))[lane];
  float4 qo;
  qo.x = __fadd_rn(x.x, __fsub_rn(q.x, x.x));
  qo.y = __fadd_rn(x.y, __fsub_rn(q.y, x.y));
  qo.z = __fadd_rn(x.z, __fsub_rn(q.z, x.z));
  qo.w = __fadd_rn(x.w, __fsub_rn(q.w, x.w));
  ((float4*)(outq + (size_t)n * DIMS))[lane] = qo;
  float dx = x.x - qo.x, dy = x.y - qo.y, dz = x.z - qo.z, dw = x.w - qo.w;
  float dd = dx * dx + dy * dy + dz * dz + dw * dw;
  float dot = x.x * q.x + x.y * q.y + x.z * q.z + x.w * q.w;
#pragma unroll
  for (int m = 1; m < 64; m <<= 1) { dd += __shfl_xor(dd, m); dot += __shfl_xor(dot, m); }
  __shared__ double sm[4], sc[4];
  if (lane == 0) {
    out_idx[n] = (float)k;
    sm[w] = (double)dd;
    float cs = dot / (fmaxf(rnorm[n], 1e-12f) * fmaxf(ncn[k], 1e-12f));
    sc[w] = (double)cs;
    atomicAdd(&hist[k], 1);
  }
  __syncthreads();
  if (t == 0) {
    qp_mse[blockIdx.x] = sm[0] + sm[1] + sm[2] + sm[3];
    qp_cos[blockIdx.x] = sc[0] + sc[1] + sc[2] + sc[3];
  }
}

// ---------------- k_pairs: bf16 MFMA pairwise distances -----------------
// scalars have 40.96 absolute threshold; bf16-hi G error ~0.3% on d2 — safe.
__global__ __launch_bounds__(256) void k_pairs(const u16* __restrict__ reparH,
                                               const float* __restrict__ sqk,
                                               double* __restrict__ pp_sum,
                                               u32* __restrict__ pp_min) {
  const int t = threadIdx.x;
  const int wid = t >> 6, lane = t & 63;
  const int r = lane & 15, q = lane >> 4;
  const int i0 = blockIdx.y * 64, j0 = blockIdx.x * 64;

  f32x4 acc[4] = {{0.f,0.f,0.f,0.f},{0.f,0.f,0.f,0.f},
                  {0.f,0.f,0.f,0.f},{0.f,0.f,0.f,0.f}};
  const u16* aph = reparH + (size_t)(i0 + wid * 16 + r) * DIMS + q * 8;
  const u16* bph = reparH + (size_t)(j0 + r) * DIMS + q * 8;

  for (int sl = 0; sl < 8; ++sl) {
    bf16x8 ah = *(const bf16x8*)(aph + sl * 32);
#pragma unroll
    for (int tile = 0; tile < 4; ++tile) {
      bf16x8 bh = *(const bf16x8*)(bph + (size_t)tile * 16 * DIMS + sl * 32);
      acc[tile] = __builtin_amdgcn_mfma_f32_16x16x32_bf16(ah, bh, acc[tile], 0, 0, 0);
    }
  }

  const int ibase = i0 + wid * 16 + q * 4;
  float sqi[4];
#pragma unroll
  for (int reg = 0; reg < 4; ++reg) sqi[reg] = sqk[ibase + reg];
  double lsum = 0.0;
  float lmin = 3.4e38f;
#pragma unroll
  for (int tile = 0; tile < 4; ++tile) {
    int j = j0 + tile * 16 + r;
    float sj = sqk[j];
#pragma unroll
    for (int reg = 0; reg < 4; ++reg) {
      int i = ibase + reg;
      if (i != j) {
        float d2 = fmaxf((sqi[reg] + sj) - 2.0f * acc[tile][reg], 0.0f);
        float dd = sqrtf(d2);
        lsum += (double)dd;
        lmin = fminf(lmin, dd);
      }
    }
  }
#pragma unroll
  for (int m = 1; m < 64; m <<= 1) {
    lsum += __shfl_xor(lsum, m);
    lmin = fminf(lmin, __shfl_xor(lmin, m));
  }
  __shared__ double sps[4];
  __shared__ float spm[4];
  if (lane == 0) { sps[wid] = lsum; spm[wid] = lmin; }
  __syncthreads();
  if (t == 0) {
    int bid = blockIdx.y * gridDim.x + blockIdx.x;
    pp_sum[bid] = sps[0] + sps[1] + sps[2] + sps[3];
    pp_min[bid] = __float_as_uint(fminf(fminf(spm[0], spm[1]), fminf(spm[2], spm[3])));
  }
}

// ---------------- k_final: scalars --------------------------------------
__global__ __launch_bounds__(256) void k_final(const double* __restrict__ qp_mse,
                                               const double* __restrict__ qp_cos,
                                               const double* __restrict__ pp_sum,
                                               const u32* __restrict__ pp_min,
                                               const int* __restrict__ hist,
                                               float* __restrict__ outs) {
  int t = threadIdx.x;
  double lm = 0, lc = 0, ld = 0, lH = 0;
  float lmin = 3.4e38f;
  for (int j = 0; j < 16; ++j) { lm += qp_mse[t + 256 * j]; lc += qp_cos[t + 256 * j]; }
  for (int j = 0; j < 4; ++j) {
    ld += pp_sum[t + 256 * j];
    lmin = fminf(lmin, __uint_as_float(pp_min[t + 256 * j]));
  }
  for (int k = t; k < KCB; k += 256) {
    float p = (float)hist[k] * (1.0f / 16384.0f);
    lH -= (double)(p * logf(p + 1e-10f));
  }
  __shared__ double sh[256];
  double mse, cosS, dS, H, mn;
  sh[t] = lm; __syncthreads();
  for (int s = 128; s; s >>= 1) { if (t < s) sh[t] += sh[t + s]; __syncthreads(); }
  mse = sh[0]; __syncthreads();
  sh[t] = lc; __syncthreads();
  for (int s = 128; s; s >>= 1) { if (t < s) sh[t] += sh[t + s]; __syncthreads(); }
  cosS = sh[0]; __syncthreads();
  sh[t] = ld; __syncthreads();
  for (int s = 128; s; s >>= 1) { if (t < s) sh[t] += sh[t + s]; __syncthreads(); }
  dS = sh[0]; __syncthreads();
  sh[t] = lH; __syncthreads();
  for (int s = 128; s; s >>= 1) { if (t < s) sh[t] += sh[t + s]; __syncthreads(); }
  H = sh[0]; __syncthreads();
  sh[t] = (double)lmin; __syncthreads();
  for (int s = 128; s; s >>= 1) { if (t < s) sh[t] = fmin(sh[t], sh[t + s]); __syncthreads(); }
  mn = sh[0];
  if (t == 0) {
    double meansq = mse / 4194304.0;
    outs[0] = (float)(0.25 * meansq);          // commitment_loss
    outs[1] = (float)meansq;                   // codebook_loss
    outs[2] = (float)exp(H);                   // perplexity
    outs[3] = (float)(cosS / 16384.0);         // selected_cosine_sim
    outs[4] = (float)(dS / (2048.0 * 2047.0)); // avg_euclidean
    outs[5] = (float)mn;                       // min_euclidean
    outs[6] = (float)sqrt(mse);                // gradient_gap
  }
}

// ---------------- launch -------------------------------------------------
extern "C" void kernel_launch(void* const* d_in, const int* in_sizes, int n_in,
                              void* d_out, int out_size, void* d_ws, size_t ws_size,
                              hipStream_t stream) {
  (void)in_sizes; (void)n_in; (void)out_size; (void)ws_size;
  const float* latent  = (const float*)d_in[0];
  const float* cb      = (const float*)d_in[1];
  const float* cmean   = (const float*)d_in[2];
  const float* cstd    = (const float*)d_in[3];
  float* out           = (float*)d_out;

  char* ws = (char*)d_ws;
  float* repar   = (float*)(ws + 0);          // 2 MB
  u16*   reparH  = (u16*)(ws + 2097152);      // 1 MB
  u16*   reparL  = (u16*)(ws + 3145728);      // 1 MB
  float* rowA    = (float*)(ws + 4194304);    // 64 KB
  float* rnorm   = (float*)(ws + 4259840);    // 64 KB
  float* sqk     = (float*)(ws + 4325376);    // 8 KB
  float* ncn     = (float*)(ws + 4333568);    // 8 KB
  int*   hist    = (int*)(ws + 4341760);      // 8 KB
  double* qp_mse = (double*)(ws + 4349952);   // 32 KB
  double* qp_cos = (double*)(ws + 4382720);   // 32 KB
  double* pp_sum = (double*)(ws + 4415488);   // 8 KB
  u32*    pp_min = (u32*)(ws + 4423680);      // 4 KB
  u64*    row_max = (u64*)(ws + 4427776);     // 128 KB

  float* out_q   = out;               // 4194304 floats
  float* out_idx = out + 4194304;     // 16384 floats
  float* out_scl = out + 4210688;     // 7 floats

  k_rowstats<<<64, 256, 0, stream>>>(latent, rowA, rnorm);
  k_codestats<<<KCB, 64, 0, stream>>>(cb, cmean, cstd, repar, reparH, reparL,
                                      sqk, ncn, hist, row_max);
  k_main<<<dim3(32, 256), 256, 0, stream>>>(latent, reparH, reparL, rowA, sqk, row_max);
  k_quant<<<NROWS / 4, 256, 0, stream>>>(latent, repar, row_max, rnorm, ncn, out_q,
                                         out_idx, qp_mse, qp_cos, hist);
  k_pairs<<<dim3(32, 32), 256, 0, stream>>>(reparH, sqk, pp_sum, pp_min);
  k_final<<<1, 256, 0, stream>>>(qp_mse, qp_cos, pp_sum, pp_min, hist, out_scl);
}

// Round 8
// 262.118 us; speedup vs baseline: 1.7721x; 1.7721x over previous
//
#include <hip/hip_runtime.h>
#include <hip/hip_bf16.h>
#include <math.h>
#include <stdint.h>

typedef unsigned int u32;
typedef unsigned long long u64;
typedef unsigned short u16;
typedef __attribute__((ext_vector_type(8))) short bf16x8;
typedef __attribute__((ext_vector_type(4))) float f32x4;

#define NROWS 16384
#define KCB   2048
#define DIMS  256

// ---------------- threefry2x32-20, key = (0, 42)  (jax.random.key(42)) ----
__device__ __forceinline__ u32 rotl32(u32 x, int r) { return (x << r) | (x >> (32 - r)); }

__device__ __forceinline__ uint2 threefry42(u32 x0, u32 x1) {
  const u32 ks0 = 0u, ks1 = 42u, ks2 = 0x1BD11BDAu ^ 42u;
  x0 += ks0; x1 += ks1;
  x0 += x1; x1 = rotl32(x1, 13); x1 ^= x0;
  x0 += x1; x1 = rotl32(x1, 15); x1 ^= x0;
  x0 += x1; x1 = rotl32(x1, 26); x1 ^= x0;
  x0 += x1; x1 = rotl32(x1, 6);  x1 ^= x0;
  x0 += ks1; x1 += ks2 + 1u;
  x0 += x1; x1 = rotl32(x1, 17); x1 ^= x0;
  x0 += x1; x1 = rotl32(x1, 29); x1 ^= x0;
  x0 += x1; x1 = rotl32(x1, 16); x1 ^= x0;
  x0 += x1; x1 = rotl32(x1, 24); x1 ^= x0;
  x0 += ks2; x1 += ks0 + 2u;
  x0 += x1; x1 = rotl32(x1, 13); x1 ^= x0;
  x0 += x1; x1 = rotl32(x1, 15); x1 ^= x0;
  x0 += x1; x1 = rotl32(x1, 26); x1 ^= x0;
  x0 += x1; x1 = rotl32(x1, 6);  x1 ^= x0;
  x0 += ks0; x1 += ks1 + 3u;
  x0 += x1; x1 = rotl32(x1, 17); x1 ^= x0;
  x0 += x1; x1 = rotl32(x1, 29); x1 ^= x0;
  x0 += x1; x1 = rotl32(x1, 16); x1 ^= x0;
  x0 += x1; x1 = rotl32(x1, 24); x1 ^= x0;
  x0 += ks1; x1 += ks2 + 4u;
  x0 += x1; x1 = rotl32(x1, 13); x1 ^= x0;
  x0 += x1; x1 = rotl32(x1, 15); x1 ^= x0;
  x0 += x1; x1 = rotl32(x1, 26); x1 ^= x0;
  x0 += x1; x1 = rotl32(x1, 6);  x1 ^= x0;
  x0 += ks2; x1 += ks0 + 5u;
  return make_uint2(x0, x1);
}

__device__ __forceinline__ u32 tf_bits_partitionable(u32 i) {
  uint2 y = threefry42(0u, i);
  return y.x ^ y.y;
}

// jax uniform(minval=FLT_MIN,maxval=1) then gumbel = -log(-log(u)), fp32
__device__ __forceinline__ float gumbel_from_bits(u32 bits) {
  float u = __uint_as_float((bits >> 9) | 0x3f800000u) - 1.0f;
  u = (u == 0.0f) ? 1.17549435082228751e-38f : u;
  return -logf(-logf(u));
}

__device__ __forceinline__ short f2bf_s(float f) {
  union { __hip_bfloat16 h; short s; } cv; cv.h = __float2bfloat16(f); return cv.s;
}
__device__ __forceinline__ float bfs2f(short s) {
  union { __hip_bfloat16 h; short s2; } cv; cv.s2 = s; return __bfloat162float(cv.h);
}

// numpy pairwise sum-of-squares, 128 floats, float4 loads, exact np order
__device__ __forceinline__ float np_sq128_v(const float4* __restrict__ p4) {
  float r0 = 0.f, r1 = 0.f, r2 = 0.f, r3 = 0.f, r4 = 0.f, r5 = 0.f, r6 = 0.f, r7 = 0.f;
  for (int i8 = 0; i8 < 16; ++i8) {
    float4 x0 = p4[2 * i8], x1 = p4[2 * i8 + 1];
    r0 = __fadd_rn(r0, __fmul_rn(x0.x, x0.x));
    r1 = __fadd_rn(r1, __fmul_rn(x0.y, x0.y));
    r2 = __fadd_rn(r2, __fmul_rn(x0.z, x0.z));
    r3 = __fadd_rn(r3, __fmul_rn(x0.w, x0.w));
    r4 = __fadd_rn(r4, __fmul_rn(x1.x, x1.x));
    r5 = __fadd_rn(r5, __fmul_rn(x1.y, x1.y));
    r6 = __fadd_rn(r6, __fmul_rn(x1.z, x1.z));
    r7 = __fadd_rn(r7, __fmul_rn(x1.w, x1.w));
  }
  return __fadd_rn(__fadd_rn(__fadd_rn(r0, r1), __fadd_rn(r2, r3)),
                   __fadd_rn(__fadd_rn(r4, r5), __fadd_rn(r6, r7)));
}

// ---------------- k_rowstats: A_n = sum x^2 (np pairwise order) ---------
__global__ __launch_bounds__(256) void k_rowstats(const float* __restrict__ flat,
                                                  float* __restrict__ rowA,
                                                  float* __restrict__ rnorm) {
  int n = blockIdx.x * 256 + threadIdx.x;
  const float4* p4 = (const float4*)(flat + (size_t)n * DIMS);
  float acc = __fadd_rn(np_sq128_v(p4), np_sq128_v(p4 + 32));
  rowA[n] = acc;
  rnorm[n] = sqrtf(acc);
}

// ---------------- k_codestats: repar fp32 + bf16 hi/lo split; sqk -------
__global__ __launch_bounds__(64) void k_codestats(const float* __restrict__ cb,
                                                  const float* __restrict__ cmean,
                                                  const float* __restrict__ cstd,
                                                  float* __restrict__ repar,
                                                  u16* __restrict__ reparH,
                                                  u16* __restrict__ reparL,
                                                  float* __restrict__ sqk,
                                                  float* __restrict__ ncn,
                                                  int* __restrict__ hist,
                                                  u64* __restrict__ row_max) {
  __shared__ float row[DIMS];
  int k = blockIdx.x;
  int lane = threadIdx.x;
  int gid = k * 64 + lane;
  if (gid < KCB) hist[gid] = 0;
  if (gid < NROWS) row_max[gid] = 0ull;
  float4 c = ((const float4*)(cb + (size_t)k * DIMS))[lane];
  float4 m = ((const float4*)cmean)[lane];
  float4 sd = ((const float4*)cstd)[lane];
  float4 r;
  r.x = __fadd_rn(m.x, __fmul_rn(sd.x, c.x));
  r.y = __fadd_rn(m.y, __fmul_rn(sd.y, c.y));
  r.z = __fadd_rn(m.z, __fmul_rn(sd.z, c.z));
  r.w = __fadd_rn(m.w, __fmul_rn(sd.w, c.w));
  ((float4*)(repar + (size_t)k * DIMS))[lane] = r;
  ((float4*)row)[lane] = r;
  float rv[4] = {r.x, r.y, r.z, r.w};
  ushort4 hi, lo;
  unsigned short hs[4], ls[4];
#pragma unroll
  for (int j = 0; j < 4; ++j) {
    short h = f2bf_s(rv[j]);
    hs[j] = (unsigned short)h;
    ls[j] = (unsigned short)f2bf_s(__fsub_rn(rv[j], bfs2f(h)));
  }
  hi.x = hs[0]; hi.y = hs[1]; hi.z = hs[2]; hi.w = hs[3];
  lo.x = ls[0]; lo.y = ls[1]; lo.z = ls[2]; lo.w = ls[3];
  ((ushort4*)(reparH + (size_t)k * DIMS))[lane] = hi;
  ((ushort4*)(reparL + (size_t)k * DIMS))[lane] = lo;
  __syncthreads();
  if (lane == 0) {
    float acc = __fadd_rn(np_sq128_v((const float4*)row),
                          np_sq128_v((const float4*)row + 32));
    sqk[k] = acc;
    ncn[k] = sqrtf(acc);
  }
}

// ---------------- k_main: LDS-staged (fragment-linear) MFMA + argmax ----
// 256 thr = 4 waves; wave w: rows r0+w*16..+15, 64 cols of this block.
// B staged per-slice into LDS in fragment order (lane*16B write AND read:
// conflict-free both ways), double-buffered, 1 barrier/slice.
__global__ __launch_bounds__(256) void k_main(const float* __restrict__ flat,
                                              const u16* __restrict__ reparH,
                                              const u16* __restrict__ reparL,
                                              const float* __restrict__ rowA,
                                              const float* __restrict__ sqk,
                                              u64* __restrict__ row_max) {
  // [buf][tile][q][r][8] : element (tile,q,r,j) = B[col=tile*16+r][k=q*8+j]
  __shared__ u16 BsH[2][4][4][16][8];   // 8 KB x2 buf
  __shared__ u16 BsL[2][4][4][16][8];

  const int t = threadIdx.x;
  const int wid = t >> 6, lane = t & 63;
  const int r = lane & 15, q = lane >> 4;
  const int r0 = blockIdx.y * 64;
  const int c0 = blockIdx.x * 64;
  const int arow = r0 + wid * 16 + r;

  // staging mapping: thread t -> (col, qs)
  const int scol = t >> 2, sq = t & 3;
  const u16* gH = reparH + (size_t)(c0 + scol) * DIMS + sq * 8;
  const u16* gL = reparL + (size_t)(c0 + scol) * DIMS + sq * 8;
  const int stile = scol >> 4, srr = scol & 15;

  f32x4 acc[4] = {{0.f,0.f,0.f,0.f},{0.f,0.f,0.f,0.f},
                  {0.f,0.f,0.f,0.f},{0.f,0.f,0.f,0.f}};

  const float* ap = flat + (size_t)arow * DIMS + q * 8;

  // preload slice 0 into buffer 0
  {
    bf16x8 vh = *(const bf16x8*)gH;
    bf16x8 vl = *(const bf16x8*)gL;
    *(bf16x8*)&BsH[0][stile][sq][srr][0] = vh;
    *(bf16x8*)&BsL[0][stile][sq][srr][0] = vl;
  }

  for (int sl = 0; sl < 8; ++sl) {
    const int buf = sl & 1;
    __syncthreads();
    // issue next slice's global loads (no use until after compute)
    bf16x8 nh, nl;
    if (sl < 7) {
      nh = *(const bf16x8*)(gH + (sl + 1) * 32);
      nl = *(const bf16x8*)(gL + (sl + 1) * 32);
    }
    // A fragment: fp32 direct load + on-the-fly hi/lo split
    float4 a0 = ((const float4*)(ap + sl * 32))[0];
    float4 a1 = ((const float4*)(ap + sl * 32))[1];
    float av[8] = {a0.x, a0.y, a0.z, a0.w, a1.x, a1.y, a1.z, a1.w};
    bf16x8 ah, al;
#pragma unroll
    for (int j = 0; j < 8; ++j) {
      short h = f2bf_s(av[j]);
      ah[j] = h;
      al[j] = f2bf_s(__fsub_rn(av[j], bfs2f(h)));
    }
#pragma unroll
    for (int tile = 0; tile < 4; ++tile) {
      bf16x8 bh = *(const bf16x8*)&BsH[buf][tile][q][r][0];
      bf16x8 bl = *(const bf16x8*)&BsL[buf][tile][q][r][0];
      acc[tile] = __builtin_amdgcn_mfma_f32_16x16x32_bf16(ah, bh, acc[tile], 0, 0, 0);
      acc[tile] = __builtin_amdgcn_mfma_f32_16x16x32_bf16(ah, bl, acc[tile], 0, 0, 0);
      acc[tile] = __builtin_amdgcn_mfma_f32_16x16x32_bf16(al, bh, acc[tile], 0, 0, 0);
    }
    if (sl < 7) {
      *(bf16x8*)&BsH[buf ^ 1][stile][sq][srr][0] = nh;
      *(bf16x8*)&BsL[buf ^ 1][stile][sq][srr][0] = nl;
    }
  }

  // epilogue: C/D layout col=lane&15, row=q*4+reg  (identical to R6/R7)
  const int nbase = r0 + wid * 16 + q * 4;
  float An[4];
#pragma unroll
  for (int reg = 0; reg < 4; ++reg) An[reg] = rowA[nbase + reg];
  float bv[4];
  int bk[4];
#pragma unroll
  for (int reg = 0; reg < 4; ++reg) { bv[reg] = -3.4e38f; bk[reg] = 0; }

#pragma unroll
  for (int tile = 0; tile < 4; ++tile) {
    int col = c0 + tile * 16 + r;
    float sqa = sqk[col];
#pragma unroll
    for (int reg = 0; reg < 4; ++reg) {
      float dot = acc[tile][reg];
      float t3 = __fsub_rn(An[reg], __fmul_rn(2.0f, dot));
      float t4 = __fadd_rn(t3, sqa);
      u32 bits = tf_bits_partitionable((u32)(nbase + reg) * 2048u + (u32)col);
      float g = gumbel_from_bits(bits);
      float v = __fsub_rn(g, t4);
      if (v > bv[reg] || (v == bv[reg] && col < bk[reg])) { bv[reg] = v; bk[reg] = col; }
    }
  }

#pragma unroll
  for (int reg = 0; reg < 4; ++reg) {
#pragma unroll
    for (int m = 1; m < 16; m <<= 1) {
      float ov = __shfl_xor(bv[reg], m);
      int ok = __shfl_xor(bk[reg], m);
      if (ov > bv[reg] || (ov == bv[reg] && ok < bk[reg])) { bv[reg] = ov; bk[reg] = ok; }
    }
    if (r == 0) {
      u32 s = __float_as_uint(bv[reg]);
      u32 uo = (s & 0x80000000u) ? ~s : (s | 0x80000000u);
      u64 key = ((u64)uo << 32) | (u64)(u32)(2047 - bk[reg]);  // max v, then min k
      atomicMax(&row_max[nbase + reg], key);
    }
  }
}

// ---------------- k_quant: decode idx, STE write, mse/cos, hist ---------
__global__ __launch_bounds__(256) void k_quant(const float* __restrict__ flat,
                                               const float* __restrict__ repar,
                                               const u64* __restrict__ row_max,
                                               const float* __restrict__ rnorm,
                                               const float* __restrict__ ncn,
                                               float* __restrict__ outq,
                                               float* __restrict__ out_idx,
                                               double* __restrict__ qp_mse,
                                               double* __restrict__ qp_cos,
                                               int* __restrict__ hist) {
  int t = threadIdx.x, w = t >> 6, lane = t & 63;
  int n = blockIdx.x * 4 + w;
  u64 key = row_max[n];
  int k = 2047 - (int)(u32)(key & 0xFFFFFFFFull);
  k = (k < 0) ? 0 : (k > (KCB - 1) ? (KCB - 1) : k);
  float4 q = ((const float4*)(repar + (size_t)k * DIMS))[lane];
  float4 x = ((const float4*)(flat + (size_t)n * DIMS))[lane];
  float4 qo;
  qo.x = __fadd_rn(x.x, __fsub_rn(q.x, x.x));
  qo.y = __fadd_rn(x.y, __fsub_rn(q.y, x.y));
  qo.z = __fadd_rn(x.z, __fsub_rn(q.z, x.z));
  qo.w = __fadd_rn(x.w, __fsub_rn(q.w, x.w));
  ((float4*)(outq + (size_t)n * DIMS))[lane] = qo;
  float dx = x.x - qo.x, dy = x.y - qo.y, dz = x.z - qo.z, dw = x.w - qo.w;
  float dd = dx * dx + dy * dy + dz * dz + dw * dw;
  float dot = x.x * q.x + x.y * q.y + x.z * q.z + x.w * q.w;
#pragma unroll
  for (int m = 1; m < 64; m <<= 1) { dd += __shfl_xor(dd, m); dot += __shfl_xor(dot, m); }
  __shared__ double sm[4], sc[4];
  if (lane == 0) {
    out_idx[n] = (float)k;
    sm[w] = (double)dd;
    float cs = dot / (fmaxf(rnorm[n], 1e-12f) * fmaxf(ncn[k], 1e-12f));
    sc[w] = (double)cs;
    atomicAdd(&hist[k], 1);
  }
  __syncthreads();
  if (t == 0) {
    qp_mse[blockIdx.x] = sm[0] + sm[1] + sm[2] + sm[3];
    qp_cos[blockIdx.x] = sc[0] + sc[1] + sc[2] + sc[3];
  }
}

// ---------------- k_pairs: bf16 MFMA pairwise distances -----------------
__global__ __launch_bounds__(256) void k_pairs(const u16* __restrict__ reparH,
                                               const float* __restrict__ sqk,
                                               double* __restrict__ pp_sum,
                                               u32* __restrict__ pp_min) {
  const int t = threadIdx.x;
  const int wid = t >> 6, lane = t & 63;
  const int r = lane & 15, q = lane >> 4;
  const int i0 = blockIdx.y * 64, j0 = blockIdx.x * 64;

  f32x4 acc[4] = {{0.f,0.f,0.f,0.f},{0.f,0.f,0.f,0.f},
                  {0.f,0.f,0.f,0.f},{0.f,0.f,0.f,0.f}};
  const u16* aph = reparH + (size_t)(i0 + wid * 16 + r) * DIMS + q * 8;
  const u16* bph = reparH + (size_t)(j0 + r) * DIMS + q * 8;

  for (int sl = 0; sl < 8; ++sl) {
    bf16x8 ah = *(const bf16x8*)(aph + sl * 32);
#pragma unroll
    for (int tile = 0; tile < 4; ++tile) {
      bf16x8 bh = *(const bf16x8*)(bph + (size_t)tile * 16 * DIMS + sl * 32);
      acc[tile] = __builtin_amdgcn_mfma_f32_16x16x32_bf16(ah, bh, acc[tile], 0, 0, 0);
    }
  }

  const int ibase = i0 + wid * 16 + q * 4;
  float sqi[4];
#pragma unroll
  for (int reg = 0; reg < 4; ++reg) sqi[reg] = sqk[ibase + reg];
  double lsum = 0.0;
  float lmin = 3.4e38f;
#pragma unroll
  for (int tile = 0; tile < 4; ++tile) {
    int j = j0 + tile * 16 + r;
    float sj = sqk[j];
#pragma unroll
    for (int reg = 0; reg < 4; ++reg) {
      int i = ibase + reg;
      if (i != j) {
        float d2 = fmaxf((sqi[reg] + sj) - 2.0f * acc[tile][reg], 0.0f);
        float dd = sqrtf(d2);
        lsum += (double)dd;
        lmin = fminf(lmin, dd);
      }
    }
  }
#pragma unroll
  for (int m = 1; m < 64; m <<= 1) {
    lsum += __shfl_xor(lsum, m);
    lmin = fminf(lmin, __shfl_xor(lmin, m));
  }
  __shared__ double sps[4];
  __shared__ float spm[4];
  if (lane == 0) { sps[wid] = lsum; spm[wid] = lmin; }
  __syncthreads();
  if (t == 0) {
    int bid = blockIdx.y * gridDim.x + blockIdx.x;
    pp_sum[bid] = sps[0] + sps[1] + sps[2] + sps[3];
    pp_min[bid] = __float_as_uint(fminf(fminf(spm[0], spm[1]), fminf(spm[2], spm[3])));
  }
}

// ---------------- k_final: scalars --------------------------------------
__global__ __launch_bounds__(256) void k_final(const double* __restrict__ qp_mse,
                                               const double* __restrict__ qp_cos,
                                               const double* __restrict__ pp_sum,
                                               const u32* __restrict__ pp_min,
                                               const int* __restrict__ hist,
                                               float* __restrict__ outs) {
  int t = threadIdx.x;
  double lm = 0, lc = 0, ld = 0, lH = 0;
  float lmin = 3.4e38f;
  for (int j = 0; j < 16; ++j) { lm += qp_mse[t + 256 * j]; lc += qp_cos[t + 256 * j]; }
  for (int j = 0; j < 4; ++j) {
    ld += pp_sum[t + 256 * j];
    lmin = fminf(lmin, __uint_as_float(pp_min[t + 256 * j]));
  }
  for (int k = t; k < KCB; k += 256) {
    float p = (float)hist[k] * (1.0f / 16384.0f);
    lH -= (double)(p * logf(p + 1e-10f));
  }
  __shared__ double sh[256];
  double mse, cosS, dS, H, mn;
  sh[t] = lm; __syncthreads();
  for (int s = 128; s; s >>= 1) { if (t < s) sh[t] += sh[t + s]; __syncthreads(); }
  mse = sh[0]; __syncthreads();
  sh[t] = lc; __syncthreads();
  for (int s = 128; s; s >>= 1) { if (t < s) sh[t] += sh[t + s]; __syncthreads(); }
  cosS = sh[0]; __syncthreads();
  sh[t] = ld; __syncthreads();
  for (int s = 128; s; s >>= 1) { if (t < s) sh[t] += sh[t + s]; __syncthreads(); }
  dS = sh[0]; __syncthreads();
  sh[t] = lH; __syncthreads();
  for (int s = 128; s; s >>= 1) { if (t < s) sh[t] += sh[t + s]; __syncthreads(); }
  H = sh[0]; __syncthreads();
  sh[t] = (double)lmin; __syncthreads();
  for (int s = 128; s; s >>= 1) { if (t < s) sh[t] = fmin(sh[t], sh[t + s]); __syncthreads(); }
  mn = sh[0];
  if (t == 0) {
    double meansq = mse / 4194304.0;
    outs[0] = (float)(0.25 * meansq);          // commitment_loss
    outs[1] = (float)meansq;                   // codebook_loss
    outs[2] = (float)exp(H);                   // perplexity
    outs[3] = (float)(cosS / 16384.0);         // selected_cosine_sim
    outs[4] = (float)(dS / (2048.0 * 2047.0)); // avg_euclidean
    outs[5] = (float)mn;                       // min_euclidean
    outs[6] = (float)sqrt(mse);                // gradient_gap
  }
}

// ---------------- launch -------------------------------------------------
extern "C" void kernel_launch(void* const* d_in, const int* in_sizes, int n_in,
                              void* d_out, int out_size, void* d_ws, size_t ws_size,
                              hipStream_t stream) {
  (void)in_sizes; (void)n_in; (void)out_size; (void)ws_size;
  const float* latent  = (const float*)d_in[0];
  const float* cb      = (const float*)d_in[1];
  const float* cmean   = (const float*)d_in[2];
  const float* cstd    = (const float*)d_in[3];
  float* out           = (float*)d_out;

  char* ws = (char*)d_ws;
  float* repar   = (float*)(ws + 0);          // 2 MB
  u16*   reparH  = (u16*)(ws + 2097152);      // 1 MB
  u16*   reparL  = (u16*)(ws + 3145728);      // 1 MB
  float* rowA    = (float*)(ws + 4194304);    // 64 KB
  float* rnorm   = (float*)(ws + 4259840);    // 64 KB
  float* sqk     = (float*)(ws + 4325376);    // 8 KB
  float* ncn     = (float*)(ws + 4333568);    // 8 KB
  int*   hist    = (int*)(ws + 4341760);      // 8 KB
  double* qp_mse = (double*)(ws + 4349952);   // 32 KB
  double* qp_cos = (double*)(ws + 4382720);   // 32 KB
  double* pp_sum = (double*)(ws + 4415488);   // 8 KB
  u32*    pp_min = (u32*)(ws + 4423680);      // 4 KB
  u64*    row_max = (u64*)(ws + 4427776);     // 128 KB

  float* out_q   = out;               // 4194304 floats
  float* out_idx = out + 4194304;     // 16384 floats
  float* out_scl = out + 4210688;     // 7 floats

  k_rowstats<<<64, 256, 0, stream>>>(latent, rowA, rnorm);
  k_codestats<<<KCB, 64, 0, stream>>>(cb, cmean, cstd, repar, reparH, reparL,
                                      sqk, ncn, hist, row_max);
  k_main<<<dim3(32, 256), 256, 0, stream>>>(latent, reparH, reparL, rowA, sqk, row_max);
  k_quant<<<NROWS / 4, 256, 0, stream>>>(latent, repar, row_max, rnorm, ncn, out_q,
                                         out_idx, qp_mse, qp_cos, hist);
  k_pairs<<<dim3(32, 32), 256, 0, stream>>>(reparH, sqk, pp_sum, pp_min);
  k_final<<<1, 256, 0, stream>>>(qp_mse, qp_cos, pp_sum, pp_min, hist, out_scl);
}